// Round 1
// baseline (156.583 us; speedup 1.0000x reference)
//
#include <hip/hip_runtime.h>
#include <math.h>

// Problem constants (B=2, H=W=64, K=4, GDIM=9)
#define NPIX 4096           // H*W
#define BATCH 2
#define BN 8192             // BATCH*NPIX
#define NSEG 16             // n-loop split for render
#define SEGLEN 256          // NPIX / NSEG
#define TWO_PI 6.28318530717958647692f

__device__ __forceinline__ float sigmoidf_(float x) {
    return 1.0f / (1.0f + __expf(-x));
}

// ---------------------------------------------------------------------------
// Kernel 1: fold conv(3->64) + head(64->36) into one 3x3 conv (36 out ch).
// comb[0..972)   : comb_w[o*27 + ci*9 + kh*3 + kw]
// comb[972..1008): comb_b[o]
// ---------------------------------------------------------------------------
__global__ __launch_bounds__(1024) void combine_kernel(
        const float* __restrict__ enc_w,   // (64,3,3,3)
        const float* __restrict__ enc_b,   // (64,)
        const float* __restrict__ head_w,  // (36,64)
        const float* __restrict__ head_b,  // (36,)
        float* __restrict__ comb) {
    int t = threadIdx.x;
    if (t < 972) {
        int o = t / 27, j = t % 27;
        float s = 0.0f;
        #pragma unroll 8
        for (int c = 0; c < 64; ++c)
            s = fmaf(head_w[o * 64 + c], enc_w[c * 27 + j], s);
        comb[t] = s;
    } else if (t < 1008) {
        int o = t - 972;
        float s = head_b[o];
        #pragma unroll 8
        for (int c = 0; c < 64; ++c)
            s = fmaf(head_w[o * 64 + c], enc_b[c], s);
        comb[972 + o] = s;
    }
}

// ---------------------------------------------------------------------------
// Kernel 2: per-pixel Gaussian parameters.
// params4[(b*NPIX+n)*2+0] = {m0, m1, ca, cb}
// params4[(b*NPIX+n)*2+1] = {cc, r, g, b}
// ---------------------------------------------------------------------------
__global__ __launch_bounds__(256) void params_kernel(
        const float* __restrict__ inp,    // (2,3,64,64)
        const float* __restrict__ comb,
        float4* __restrict__ params4) {
    __shared__ float cw[1008];
    int t = threadIdx.x;
    for (int i = t; i < 1008; i += 256) cw[i] = comb[i];
    __syncthreads();

    int gid = blockIdx.x * 256 + t;      // 0..8191
    int b = gid >> 12;
    int n = gid & 4095;
    int h = n >> 6, w = n & 63;

    // 3x3x3 neighborhood, zero-padded (SAME)
    float x[27];
    const float* base = inp + b * 3 * NPIX;
    #pragma unroll
    for (int ci = 0; ci < 3; ++ci) {
        #pragma unroll
        for (int dh = -1; dh <= 1; ++dh) {
            #pragma unroll
            for (int dw = -1; dw <= 1; ++dw) {
                int hh = h + dh, ww = w + dw;
                float v = 0.0f;
                if (hh >= 0 && hh < 64 && ww >= 0 && ww < 64)
                    v = base[ci * NPIX + hh * 64 + ww];
                x[ci * 9 + (dh + 1) * 3 + (dw + 1)] = v;
            }
        }
    }

    // 36-channel prediction
    float pred[36];
    #pragma unroll
    for (int o = 0; o < 36; ++o) {
        float s = cw[972 + o];
        #pragma unroll
        for (int j = 0; j < 27; ++j)
            s = fmaf(x[j], cw[o * 27 + j], s);
        pred[o] = s;
    }

    // softmax over K=4 (w_logits at g=8)
    float wl0 = pred[8], wl1 = pred[17], wl2 = pred[26], wl3 = pred[35];
    float mx = fmaxf(fmaxf(wl0, wl1), fmaxf(wl2, wl3));
    float e0 = __expf(wl0 - mx), e1 = __expf(wl1 - mx);
    float e2 = __expf(wl2 - mx), e3 = __expf(wl3 - mx);
    float inv = 1.0f / (e0 + e1 + e2 + e3);
    float wk[4] = {e0 * inv, e1 * inv, e2 * inv, e3 * inv};

    float r = 0.f, g = 0.f, bl = 0.f;
    float theta = 0.f, s0 = 0.f, s1 = 0.f, o0 = 0.f, o1 = 0.f;
    #pragma unroll
    for (int k = 0; k < 4; ++k) {
        float wkk = wk[k];
        r  = fmaf(wkk, pred[k * 9 + 0], r);
        g  = fmaf(wkk, pred[k * 9 + 1], g);
        bl = fmaf(wkk, pred[k * 9 + 2], bl);
        theta = fmaf(wkk, sigmoidf_(pred[k * 9 + 3]) * TWO_PI, theta);
        s0 = fmaf(wkk, sigmoidf_(pred[k * 9 + 4]) * 0.5f + 1e-6f, s0);
        s1 = fmaf(wkk, sigmoidf_(pred[k * 9 + 5]) * 0.5f + 1e-6f, s1);
        o0 = fmaf(wkk, tanhf(pred[k * 9 + 6]), o0);
        o1 = fmaf(wkk, tanhf(pred[k * 9 + 7]), o1);
    }

    float isx = 1.0f / (s0 * s0);
    float isy = 1.0f / (s1 * s1);
    float c_, s_;
    __sincosf(theta, &s_, &c_);
    float ca = c_ * c_ * isx + s_ * s_ * isy;
    float cb = c_ * s_ * (isx - isy);
    float cc = s_ * s_ * isx + c_ * c_ * isy;

    float coord0 = (float)(n & 63) * 0.03125f - 1.0f;   // 2*w/W - 1
    float coord1 = (float)(n >> 6) * 0.03125f - 1.0f;   // 2*h/H - 1
    float m0 = coord0 + o0 * 0.03125f - 0.015625f;      // + 2*off/W - 1/W
    float m1 = coord1 + o1 * 0.03125f - 0.015625f;

    params4[gid * 2 + 0] = make_float4(m0, m1, ca, cb);
    params4[gid * 2 + 1] = make_float4(cc, r, g, bl);
}

// ---------------------------------------------------------------------------
// Kernel 3: render partials. Block = (b, ptile, seg); 256 threads, one p each.
// partial[(seg*BN + b*NPIX + p)*3 + {0,1,2}]
// ---------------------------------------------------------------------------
__global__ __launch_bounds__(256) void render_kernel(
        const float4* __restrict__ params4,
        float* __restrict__ partial) {
    __shared__ float4 lp[SEGLEN * 2];
    int t = threadIdx.x;
    int bi = blockIdx.x;
    int seg   = bi & (NSEG - 1);
    int ptile = (bi >> 4) & 15;
    int b     = bi >> 8;

    int nbase4 = (b * NPIX + seg * SEGLEN) * 2;  // float4 index
    lp[t]       = params4[nbase4 + t];
    lp[t + 256] = params4[nbase4 + 256 + t];
    __syncthreads();

    int p = ptile * 256 + t;
    float px = (float)(p & 63) * 0.03125f - 1.0f;
    float py = (float)(p >> 6) * 0.03125f - 1.0f;

    float ar = 0.f, ag = 0.f, ab = 0.f;
    #pragma unroll 8
    for (int j = 0; j < SEGLEN; ++j) {
        float4 q0 = lp[2 * j];
        float4 q1 = lp[2 * j + 1];
        float dx = px - q0.x;
        float dy = py - q0.y;
        float sigma = fmaf(0.5f * q0.z, dx * dx,
                      fmaf(0.5f * q1.x, dy * dy, q0.w * (dx * dy)));
        float alpha = (sigma >= 0.0f) ? __expf(-sigma) : 0.0f;
        ar = fmaf(alpha, q1.y, ar);
        ag = fmaf(alpha, q1.z, ag);
        ab = fmaf(alpha, q1.w, ab);
    }

    int idx = (seg * BN + b * NPIX + p) * 3;
    partial[idx + 0] = ar;
    partial[idx + 1] = ag;
    partial[idx + 2] = ab;
}

// ---------------------------------------------------------------------------
// Kernel 4: reduce partials, clip, write NCHW output.
// ---------------------------------------------------------------------------
__global__ __launch_bounds__(256) void reduce_kernel(
        const float* __restrict__ partial,
        float* __restrict__ out) {
    int bp = blockIdx.x * 256 + threadIdx.x;   // 0..8191
    int b = bp >> 12, p = bp & 4095;
    float r = 0.f, g = 0.f, bl = 0.f;
    #pragma unroll
    for (int s = 0; s < NSEG; ++s) {
        int idx = (s * BN + bp) * 3;
        r  += partial[idx + 0];
        g  += partial[idx + 1];
        bl += partial[idx + 2];
    }
    r  = fminf(fmaxf(r, 0.0f), 1.0f);
    g  = fminf(fmaxf(g, 0.0f), 1.0f);
    bl = fminf(fmaxf(bl, 0.0f), 1.0f);
    out[(b * 3 + 0) * NPIX + p] = r;
    out[(b * 3 + 1) * NPIX + p] = g;
    out[(b * 3 + 2) * NPIX + p] = bl;
}

// ---------------------------------------------------------------------------
extern "C" void kernel_launch(void* const* d_in, const int* in_sizes, int n_in,
                              void* d_out, int out_size, void* d_ws, size_t ws_size,
                              hipStream_t stream) {
    const float* inp    = (const float*)d_in[0];  // (2,3,64,64)
    const float* enc_w  = (const float*)d_in[1];  // (64,3,3,3)
    const float* enc_b  = (const float*)d_in[2];  // (64,)
    const float* head_w = (const float*)d_in[3];  // (36,64)
    const float* head_b = (const float*)d_in[4];  // (36,)
    float* out = (float*)d_out;                   // (2,3,64,64)

    float* ws = (float*)d_ws;
    float* comb    = ws;                 // 1024 floats (1008 used)
    float* params  = ws + 1024;          // BN*8 = 65536 floats
    float* partial = ws + 1024 + 65536;  // NSEG*BN*3 = 393216 floats
    float4* params4 = (float4*)params;

    combine_kernel<<<1, 1024, 0, stream>>>(enc_w, enc_b, head_w, head_b, comb);
    params_kernel<<<BN / 256, 256, 0, stream>>>(inp, comb, params4);
    render_kernel<<<BATCH * (NPIX / 256) * NSEG, 256, 0, stream>>>(params4, partial);
    reduce_kernel<<<BN / 256, 256, 0, stream>>>(partial, out);
}

// Round 2
// 97.998 us; speedup vs baseline: 1.5978x; 1.5978x over previous
//
#include <hip/hip_runtime.h>
#include <math.h>

// Problem constants (B=2, H=W=64, K=4, GDIM=9)
#define NPIX 4096           // H*W
#define BATCH 2
#define BN 8192             // BATCH*NPIX
#define NSEG 16             // n-loop split for render
#define SEGLEN 256          // NPIX / NSEG
#define TWO_PI 6.28318530717958647692f

__device__ __forceinline__ float sigmoidf_(float x) {
    return 1.0f / (1.0f + __expf(-x));
}
// tanh via exp: 1 - 2/(e^{2x}+1). Saturates correctly at +/-1.
__device__ __forceinline__ float tanhf_(float x) {
    return 1.0f - 2.0f / (__expf(2.0f * x) + 1.0f);
}

// ---------------------------------------------------------------------------
// Kernel 1: fold conv(3->64) + head(64->36) into one 3x3 conv (36 out ch).
// comb[0..972)   : comb_w[o*27 + ci*9 + kh*3 + kw]
// comb[972..1008): comb_b[o]
// ---------------------------------------------------------------------------
__global__ __launch_bounds__(1024) void combine_kernel(
        const float* __restrict__ enc_w,   // (64,3,3,3)
        const float* __restrict__ enc_b,   // (64,)
        const float* __restrict__ head_w,  // (36,64)
        const float* __restrict__ head_b,  // (36,)
        float* __restrict__ comb) {
    int t = threadIdx.x;
    if (t < 972) {
        int o = t / 27, j = t % 27;
        float s = 0.0f;
        #pragma unroll 8
        for (int c = 0; c < 64; ++c)
            s = fmaf(head_w[o * 64 + c], enc_w[c * 27 + j], s);
        comb[t] = s;
    } else if (t < 1008) {
        int o = t - 972;
        float s = head_b[o];
        #pragma unroll 8
        for (int c = 0; c < 64; ++c)
            s = fmaf(head_w[o * 64 + c], enc_b[c], s);
        comb[972 + o] = s;
    }
}

// ---------------------------------------------------------------------------
// Kernel 2: per-(pixel,k) Gaussian parameters. 4 lanes per pixel (k = tid&3),
// softmax + weighted sums via 4-lane shfl_xor butterflies; lane k==0 writes.
// params4[pix*2+0] = {m0, m1, ca, cb} ; params4[pix*2+1] = {cc, r, g, b}
// ---------------------------------------------------------------------------
__global__ __launch_bounds__(256) void params_kernel(
        const float* __restrict__ inp,    // (2,3,64,64)
        const float* __restrict__ comb,
        float4* __restrict__ params4) {
    __shared__ float cw[1008];
    int t = threadIdx.x;
    for (int i = t; i < 1008; i += 256) cw[i] = comb[i];
    __syncthreads();

    int gid = blockIdx.x * 256 + t;      // 0..32767
    int k   = gid & 3;
    int pix = gid >> 2;                  // 0..8191
    int b = pix >> 12;
    int n = pix & 4095;
    int h = n >> 6, w = n & 63;

    // 3x3x3 neighborhood, zero-padded (SAME)
    float x[27];
    const float* base = inp + b * 3 * NPIX;
    #pragma unroll
    for (int ci = 0; ci < 3; ++ci) {
        #pragma unroll
        for (int dh = -1; dh <= 1; ++dh) {
            #pragma unroll
            for (int dw = -1; dw <= 1; ++dw) {
                int hh = h + dh, ww = w + dw;
                float v = 0.0f;
                if (hh >= 0 && hh < 64 && ww >= 0 && ww < 64)
                    v = base[ci * NPIX + hh * 64 + ww];
                x[ci * 9 + (dh + 1) * 3 + (dw + 1)] = v;
            }
        }
    }

    // 9 channels for this k
    const int ob = k * 9;
    float pr[9];
    #pragma unroll
    for (int j = 0; j < 9; ++j) {
        float s = cw[972 + ob + j];
        #pragma unroll
        for (int q = 0; q < 27; ++q)
            s = fmaf(x[q], cw[(ob + j) * 27 + q], s);
        pr[j] = s;
    }

    // softmax over the 4-lane group (lane layout: pix*4 + k)
    float wl = pr[8];
    float mx = fmaxf(wl, __shfl_xor(wl, 1));
    mx = fmaxf(mx, __shfl_xor(mx, 2));
    float e = __expf(wl - mx);
    float se = e + __shfl_xor(e, 1);
    se += __shfl_xor(se, 2);
    float wk = e / se;

    // this-k weighted contributions
    float r  = wk * pr[0];
    float g  = wk * pr[1];
    float bl = wk * pr[2];
    float th = wk * (sigmoidf_(pr[3]) * TWO_PI);
    float s0 = wk * (sigmoidf_(pr[4]) * 0.5f + 1e-6f);
    float s1 = wk * (sigmoidf_(pr[5]) * 0.5f + 1e-6f);
    float o0 = wk * tanhf_(pr[6]);
    float o1 = wk * tanhf_(pr[7]);

    // sum across the 4-lane group
    #define GSUM(v) { v += __shfl_xor(v, 1); v += __shfl_xor(v, 2); }
    GSUM(r) GSUM(g) GSUM(bl) GSUM(th) GSUM(s0) GSUM(s1) GSUM(o0) GSUM(o1)
    #undef GSUM

    if (k == 0) {
        float isx = 1.0f / (s0 * s0);
        float isy = 1.0f / (s1 * s1);
        float c_, s_;
        __sincosf(th, &s_, &c_);
        float ca = c_ * c_ * isx + s_ * s_ * isy;
        float cb = c_ * s_ * (isx - isy);
        float cc = s_ * s_ * isx + c_ * c_ * isy;

        float coord0 = (float)(n & 63) * 0.03125f - 1.0f;   // 2*w/W - 1
        float coord1 = (float)(n >> 6) * 0.03125f - 1.0f;   // 2*h/H - 1
        float m0 = coord0 + o0 * 0.03125f - 0.015625f;      // + 2*off/W - 1/W
        float m1 = coord1 + o1 * 0.03125f - 0.015625f;

        params4[pix * 2 + 0] = make_float4(m0, m1, ca, cb);
        params4[pix * 2 + 1] = make_float4(cc, r, g, bl);
    }
}

// ---------------------------------------------------------------------------
// Kernel 3: render partials. Block = (b, ptile, seg); 256 threads, one p each.
// partial[(seg*BN + b*NPIX + p)*3 + {0,1,2}]
// ---------------------------------------------------------------------------
__global__ __launch_bounds__(256) void render_kernel(
        const float4* __restrict__ params4,
        float* __restrict__ partial) {
    __shared__ float4 lp[SEGLEN * 2];
    int t = threadIdx.x;
    int bi = blockIdx.x;
    int seg   = bi & (NSEG - 1);
    int ptile = (bi >> 4) & 15;
    int b     = bi >> 8;

    int nbase4 = (b * NPIX + seg * SEGLEN) * 2;  // float4 index
    lp[t]       = params4[nbase4 + t];
    lp[t + 256] = params4[nbase4 + 256 + t];
    __syncthreads();

    int p = ptile * 256 + t;
    float px = (float)(p & 63) * 0.03125f - 1.0f;
    float py = (float)(p >> 6) * 0.03125f - 1.0f;

    float ar = 0.f, ag = 0.f, ab = 0.f;
    #pragma unroll 8
    for (int j = 0; j < SEGLEN; ++j) {
        float4 q0 = lp[2 * j];
        float4 q1 = lp[2 * j + 1];
        float dx = px - q0.x;
        float dy = py - q0.y;
        float sigma = fmaf(0.5f * q0.z, dx * dx,
                      fmaf(0.5f * q1.x, dy * dy, q0.w * (dx * dy)));
        float alpha = (sigma >= 0.0f) ? __expf(-sigma) : 0.0f;
        ar = fmaf(alpha, q1.y, ar);
        ag = fmaf(alpha, q1.z, ag);
        ab = fmaf(alpha, q1.w, ab);
    }

    int idx = (seg * BN + b * NPIX + p) * 3;
    partial[idx + 0] = ar;
    partial[idx + 1] = ag;
    partial[idx + 2] = ab;
}

// ---------------------------------------------------------------------------
// Kernel 4: reduce partials, clip, write NCHW output.
// ---------------------------------------------------------------------------
__global__ __launch_bounds__(256) void reduce_kernel(
        const float* __restrict__ partial,
        float* __restrict__ out) {
    int bp = blockIdx.x * 256 + threadIdx.x;   // 0..8191
    int b = bp >> 12, p = bp & 4095;
    float r = 0.f, g = 0.f, bl = 0.f;
    #pragma unroll
    for (int s = 0; s < NSEG; ++s) {
        int idx = (s * BN + bp) * 3;
        r  += partial[idx + 0];
        g  += partial[idx + 1];
        bl += partial[idx + 2];
    }
    r  = fminf(fmaxf(r, 0.0f), 1.0f);
    g  = fminf(fmaxf(g, 0.0f), 1.0f);
    bl = fminf(fmaxf(bl, 0.0f), 1.0f);
    out[(b * 3 + 0) * NPIX + p] = r;
    out[(b * 3 + 1) * NPIX + p] = g;
    out[(b * 3 + 2) * NPIX + p] = bl;
}

// ---------------------------------------------------------------------------
extern "C" void kernel_launch(void* const* d_in, const int* in_sizes, int n_in,
                              void* d_out, int out_size, void* d_ws, size_t ws_size,
                              hipStream_t stream) {
    const float* inp    = (const float*)d_in[0];  // (2,3,64,64)
    const float* enc_w  = (const float*)d_in[1];  // (64,3,3,3)
    const float* enc_b  = (const float*)d_in[2];  // (64,)
    const float* head_w = (const float*)d_in[3];  // (36,64)
    const float* head_b = (const float*)d_in[4];  // (36,)
    float* out = (float*)d_out;                   // (2,3,64,64)

    float* ws = (float*)d_ws;
    float* comb    = ws;                 // 1024 floats (1008 used)
    float* params  = ws + 1024;          // BN*8 = 65536 floats
    float* partial = ws + 1024 + 65536;  // NSEG*BN*3 = 393216 floats
    float4* params4 = (float4*)params;

    combine_kernel<<<1, 1024, 0, stream>>>(enc_w, enc_b, head_w, head_b, comb);
    params_kernel<<<(BN * 4) / 256, 256, 0, stream>>>(inp, comb, params4);
    render_kernel<<<BATCH * (NPIX / 256) * NSEG, 256, 0, stream>>>(params4, partial);
    reduce_kernel<<<BN / 256, 256, 0, stream>>>(partial, out);
}

// Round 4
// 93.291 us; speedup vs baseline: 1.6784x; 1.0504x over previous
//
#include <hip/hip_runtime.h>
#include <math.h>

// Problem constants (B=2, H=W=64, K=4, GDIM=9)
#define NPIX 4096           // H*W
#define BATCH 2
#define BN 8192             // BATCH*NPIX
#define NSEG 16             // n-loop split for render
#define SEGLEN 256          // NPIX / NSEG
#define TWO_PI 6.28318530717958647692f
#define LOG2E 1.44269504088896340736f

__device__ __forceinline__ float sigmoidf_(float x) {
    return 1.0f / (1.0f + __expf(-x));
}
// tanh via exp: 1 - 2/(e^{2x}+1). Saturates correctly at +/-1.
__device__ __forceinline__ float tanhf_(float x) {
    return 1.0f - 2.0f / (__expf(2.0f * x) + 1.0f);
}

// ---------------------------------------------------------------------------
// Kernel 1: per-(pixel,k) Gaussian parameters, with the conv(3->64)+head(64->36)
// weight fold computed per-block into LDS (removes the separate combine kernel;
// 16 KB of weights are L1/L2-resident across the 128 blocks).
// 4 lanes per pixel (k = tid&3); softmax + weighted sums via 4-lane shfl_xor.
// Stored conic is pre-scaled by -0.5*log2(e) so render uses raw exp2:
// params4[pix*2+0] = {m0, m1, na, nb} ; params4[pix*2+1] = {nc, r, g, b}
//   where na=-0.5*ca*log2e, nb=-cb*log2e, nc=-0.5*cc*log2e.
// ---------------------------------------------------------------------------
__global__ __launch_bounds__(256) void params_kernel(
        const float* __restrict__ inp,     // (2,3,64,64)
        const float* __restrict__ enc_w,   // (64,3,3,3)
        const float* __restrict__ enc_b,   // (64,)
        const float* __restrict__ head_w,  // (36,64)
        const float* __restrict__ head_b,  // (36,)
        float4* __restrict__ params4) {
    __shared__ float cw[1008];  // [0,972): comb_w[o*27+j], [972,1008): comb_b[o]
    int t = threadIdx.x;
    #pragma unroll
    for (int i = 0; i < 4; ++i) {
        int e = t + i * 256;
        if (e < 972) {
            int o = e / 27, j = e % 27;
            float s = 0.0f;
            #pragma unroll 8
            for (int c = 0; c < 64; ++c)
                s = fmaf(head_w[o * 64 + c], enc_w[c * 27 + j], s);
            cw[e] = s;
        } else if (e < 1008) {
            int o = e - 972;
            float s = head_b[o];
            #pragma unroll 8
            for (int c = 0; c < 64; ++c)
                s = fmaf(head_w[o * 64 + c], enc_b[c], s);
            cw[e] = s;
        }
    }
    __syncthreads();

    int gid = blockIdx.x * 256 + t;      // 0..32767
    int k   = gid & 3;
    int pix = gid >> 2;                  // 0..8191
    int b = pix >> 12;
    int n = pix & 4095;
    int h = n >> 6, w = n & 63;

    // 3x3x3 neighborhood, zero-padded (SAME)
    float x[27];
    const float* base = inp + b * 3 * NPIX;
    #pragma unroll
    for (int ci = 0; ci < 3; ++ci) {
        #pragma unroll
        for (int dh = -1; dh <= 1; ++dh) {
            #pragma unroll
            for (int dw = -1; dw <= 1; ++dw) {
                int hh = h + dh, ww = w + dw;
                float v = 0.0f;
                if (hh >= 0 && hh < 64 && ww >= 0 && ww < 64)
                    v = base[ci * NPIX + hh * 64 + ww];
                x[ci * 9 + (dh + 1) * 3 + (dw + 1)] = v;
            }
        }
    }

    // 9 channels for this k
    const int ob = k * 9;
    float pr[9];
    #pragma unroll
    for (int j = 0; j < 9; ++j) {
        float s = cw[972 + ob + j];
        #pragma unroll
        for (int q = 0; q < 27; ++q)
            s = fmaf(x[q], cw[(ob + j) * 27 + q], s);
        pr[j] = s;
    }

    // softmax over the 4-lane group (lane layout: pix*4 + k)
    float wl = pr[8];
    float mx = fmaxf(wl, __shfl_xor(wl, 1));
    mx = fmaxf(mx, __shfl_xor(mx, 2));
    float e = __expf(wl - mx);
    float se = e + __shfl_xor(e, 1);
    se += __shfl_xor(se, 2);
    float wk = e / se;

    // this-k weighted contributions
    float r  = wk * pr[0];
    float g  = wk * pr[1];
    float bl = wk * pr[2];
    float th = wk * (sigmoidf_(pr[3]) * TWO_PI);
    float s0 = wk * (sigmoidf_(pr[4]) * 0.5f + 1e-6f);
    float s1 = wk * (sigmoidf_(pr[5]) * 0.5f + 1e-6f);
    float o0 = wk * tanhf_(pr[6]);
    float o1 = wk * tanhf_(pr[7]);

    // sum across the 4-lane group
    #define GSUM(v) { v += __shfl_xor(v, 1); v += __shfl_xor(v, 2); }
    GSUM(r) GSUM(g) GSUM(bl) GSUM(th) GSUM(s0) GSUM(s1) GSUM(o0) GSUM(o1)
    #undef GSUM

    if (k == 0) {
        float isx = 1.0f / (s0 * s0);
        float isy = 1.0f / (s1 * s1);
        float c_, s_;
        __sincosf(th, &s_, &c_);
        float ca = c_ * c_ * isx + s_ * s_ * isy;
        float cb = c_ * s_ * (isx - isy);
        float cc = s_ * s_ * isx + c_ * c_ * isy;

        float coord0 = (float)(n & 63) * 0.03125f - 1.0f;   // 2*w/W - 1
        float coord1 = (float)(n >> 6) * 0.03125f - 1.0f;   // 2*h/H - 1
        float m0 = coord0 + o0 * 0.03125f - 0.015625f;      // + 2*off/W - 1/W
        float m1 = coord1 + o1 * 0.03125f - 0.015625f;

        float na = -(0.5f * LOG2E) * ca;
        float nb = -LOG2E * cb;
        float nc = -(0.5f * LOG2E) * cc;

        params4[pix * 2 + 0] = make_float4(m0, m1, na, nb);
        params4[pix * 2 + 1] = make_float4(nc, r, g, bl);
    }
}

// ---------------------------------------------------------------------------
// Kernel 2: render partials. Block = (b, ptile, seg); 256 threads, one p each.
// alpha = exp2(na*dx^2 + nc*dy^2 + nb*dx*dy) gated on t<=0  (t = -sigma*log2e)
// partial[(seg*BN + b*NPIX + p)*3 + {0,1,2}]
// ---------------------------------------------------------------------------
__global__ __launch_bounds__(256) void render_kernel(
        const float4* __restrict__ params4,
        float* __restrict__ partial) {
    __shared__ float4 lp[SEGLEN * 2];
    int t = threadIdx.x;
    int bi = blockIdx.x;
    int seg   = bi & (NSEG - 1);
    int ptile = (bi >> 4) & 15;
    int b     = bi >> 8;

    int nbase4 = (b * NPIX + seg * SEGLEN) * 2;  // float4 index
    lp[t]       = params4[nbase4 + t];
    lp[t + 256] = params4[nbase4 + 256 + t];
    __syncthreads();

    int p = ptile * 256 + t;
    float px = (float)(p & 63) * 0.03125f - 1.0f;
    float py = (float)(p >> 6) * 0.03125f - 1.0f;

    float ar = 0.f, ag = 0.f, ab = 0.f;
    #pragma unroll 8
    for (int j = 0; j < SEGLEN; ++j) {
        float4 q0 = lp[2 * j];
        float4 q1 = lp[2 * j + 1];
        float dx = px - q0.x;
        float dy = py - q0.y;
        float tt = fmaf(q0.z, dx * dx,
                   fmaf(q1.x, dy * dy, q0.w * (dx * dy)));
        float alpha = (tt <= 0.0f) ? __builtin_amdgcn_exp2f(tt) : 0.0f;
        ar = fmaf(alpha, q1.y, ar);
        ag = fmaf(alpha, q1.z, ag);
        ab = fmaf(alpha, q1.w, ab);
    }

    int idx = (seg * BN + b * NPIX + p) * 3;
    partial[idx + 0] = ar;
    partial[idx + 1] = ag;
    partial[idx + 2] = ab;
}

// ---------------------------------------------------------------------------
// Kernel 3: reduce partials, clip, write NCHW output.
// ---------------------------------------------------------------------------
__global__ __launch_bounds__(256) void reduce_kernel(
        const float* __restrict__ partial,
        float* __restrict__ out) {
    int bp = blockIdx.x * 256 + threadIdx.x;   // 0..8191
    int b = bp >> 12, p = bp & 4095;
    float r = 0.f, g = 0.f, bl = 0.f;
    #pragma unroll
    for (int s = 0; s < NSEG; ++s) {
        int idx = (s * BN + bp) * 3;
        r  += partial[idx + 0];
        g  += partial[idx + 1];
        bl += partial[idx + 2];
    }
    r  = fminf(fmaxf(r, 0.0f), 1.0f);
    g  = fminf(fmaxf(g, 0.0f), 1.0f);
    bl = fminf(fmaxf(bl, 0.0f), 1.0f);
    out[(b * 3 + 0) * NPIX + p] = r;
    out[(b * 3 + 1) * NPIX + p] = g;
    out[(b * 3 + 2) * NPIX + p] = bl;
}

// ---------------------------------------------------------------------------
extern "C" void kernel_launch(void* const* d_in, const int* in_sizes, int n_in,
                              void* d_out, int out_size, void* d_ws, size_t ws_size,
                              hipStream_t stream) {
    const float* inp    = (const float*)d_in[0];  // (2,3,64,64)
    const float* enc_w  = (const float*)d_in[1];  // (64,3,3,3)
    const float* enc_b  = (const float*)d_in[2];  // (64,)
    const float* head_w = (const float*)d_in[3];  // (36,64)
    const float* head_b = (const float*)d_in[4];  // (36,)
    float* out = (float*)d_out;                   // (2,3,64,64)

    float* ws = (float*)d_ws;
    float* params  = ws;                 // BN*8 = 65536 floats
    float* partial = ws + 65536;         // NSEG*BN*3 = 393216 floats
    float4* params4 = (float4*)params;

    params_kernel<<<(BN * 4) / 256, 256, 0, stream>>>(inp, enc_w, enc_b,
                                                      head_w, head_b, params4);
    render_kernel<<<BATCH * (NPIX / 256) * NSEG, 256, 0, stream>>>(params4, partial);
    reduce_kernel<<<BN / 256, 256, 0, stream>>>(partial, out);
}

// Round 5
// 90.476 us; speedup vs baseline: 1.7307x; 1.0311x over previous
//
#include <hip/hip_runtime.h>
#include <math.h>

// Problem constants (B=2, H=W=64, K=4, GDIM=9)
#define NPIX 4096           // H*W
#define BATCH 2
#define TWO_PI 6.28318530717958647692f
#define LOG2E 1.44269504088896340736f

// Fused render geometry: block = (b, ptile of 32 pixels), 1024 threads.
// wave: lane = 32 segs x 2 pixels; seg handles 128 Gaussians.
#define RSEG 32
#define RSEGLEN 128         // NPIX / RSEG
#define SEG_STRIDE4 257     // float4 stride per segment: 128*2 + 1 (16B pad)

__device__ __forceinline__ float sigmoidf_(float x) {
    return 1.0f / (1.0f + __expf(-x));
}
// tanh via exp: 1 - 2/(e^{2x}+1). Saturates correctly at +/-1.
__device__ __forceinline__ float tanhf_(float x) {
    return 1.0f - 2.0f / (__expf(2.0f * x) + 1.0f);
}

// ---------------------------------------------------------------------------
// Kernel 1: per-(pixel,k) Gaussian parameters; conv(3->64)+head(64->36) weights
// folded per-block into LDS. 4 lanes per pixel (k = tid&3); softmax + weighted
// sums via 4-lane shfl_xor. Conic pre-scaled by -0.5*log2e so render is exp2:
// params4[pix*2+0] = {m0, m1, na, nb} ; params4[pix*2+1] = {nc, r, g, b}
// ---------------------------------------------------------------------------
__global__ __launch_bounds__(256) void params_kernel(
        const float* __restrict__ inp,     // (2,3,64,64)
        const float* __restrict__ enc_w,   // (64,3,3,3)
        const float* __restrict__ enc_b,   // (64,)
        const float* __restrict__ head_w,  // (36,64)
        const float* __restrict__ head_b,  // (36,)
        float4* __restrict__ params4) {
    __shared__ float cw[1008];  // [0,972): comb_w[o*27+j], [972,1008): comb_b[o]
    int t = threadIdx.x;
    #pragma unroll
    for (int i = 0; i < 4; ++i) {
        int e = t + i * 256;
        if (e < 972) {
            int o = e / 27, j = e % 27;
            float s = 0.0f;
            #pragma unroll 8
            for (int c = 0; c < 64; ++c)
                s = fmaf(head_w[o * 64 + c], enc_w[c * 27 + j], s);
            cw[e] = s;
        } else if (e < 1008) {
            int o = e - 972;
            float s = head_b[o];
            #pragma unroll 8
            for (int c = 0; c < 64; ++c)
                s = fmaf(head_w[o * 64 + c], enc_b[c], s);
            cw[e] = s;
        }
    }
    __syncthreads();

    int gid = blockIdx.x * 256 + t;      // 0..32767
    int k   = gid & 3;
    int pix = gid >> 2;                  // 0..8191
    int b = pix >> 12;
    int n = pix & 4095;
    int h = n >> 6, w = n & 63;

    // 3x3x3 neighborhood, zero-padded (SAME)
    float x[27];
    const float* base = inp + b * 3 * NPIX;
    #pragma unroll
    for (int ci = 0; ci < 3; ++ci) {
        #pragma unroll
        for (int dh = -1; dh <= 1; ++dh) {
            #pragma unroll
            for (int dw = -1; dw <= 1; ++dw) {
                int hh = h + dh, ww = w + dw;
                float v = 0.0f;
                if (hh >= 0 && hh < 64 && ww >= 0 && ww < 64)
                    v = base[ci * NPIX + hh * 64 + ww];
                x[ci * 9 + (dh + 1) * 3 + (dw + 1)] = v;
            }
        }
    }

    // 9 channels for this k
    const int ob = k * 9;
    float pr[9];
    #pragma unroll
    for (int j = 0; j < 9; ++j) {
        float s = cw[972 + ob + j];
        #pragma unroll
        for (int q = 0; q < 27; ++q)
            s = fmaf(x[q], cw[(ob + j) * 27 + q], s);
        pr[j] = s;
    }

    // softmax over the 4-lane group (lane layout: pix*4 + k)
    float wl = pr[8];
    float mx = fmaxf(wl, __shfl_xor(wl, 1));
    mx = fmaxf(mx, __shfl_xor(mx, 2));
    float e = __expf(wl - mx);
    float se = e + __shfl_xor(e, 1);
    se += __shfl_xor(se, 2);
    float wk = e / se;

    // this-k weighted contributions
    float r  = wk * pr[0];
    float g  = wk * pr[1];
    float bl = wk * pr[2];
    float th = wk * (sigmoidf_(pr[3]) * TWO_PI);
    float s0 = wk * (sigmoidf_(pr[4]) * 0.5f + 1e-6f);
    float s1 = wk * (sigmoidf_(pr[5]) * 0.5f + 1e-6f);
    float o0 = wk * tanhf_(pr[6]);
    float o1 = wk * tanhf_(pr[7]);

    // sum across the 4-lane group
    #define GSUM2(v) { v += __shfl_xor(v, 1); v += __shfl_xor(v, 2); }
    GSUM2(r) GSUM2(g) GSUM2(bl) GSUM2(th) GSUM2(s0) GSUM2(s1) GSUM2(o0) GSUM2(o1)
    #undef GSUM2

    if (k == 0) {
        float isx = 1.0f / (s0 * s0);
        float isy = 1.0f / (s1 * s1);
        float c_, s_;
        __sincosf(th, &s_, &c_);
        float ca = c_ * c_ * isx + s_ * s_ * isy;
        float cb = c_ * s_ * (isx - isy);
        float cc = s_ * s_ * isx + c_ * c_ * isy;

        float coord0 = (float)(n & 63) * 0.03125f - 1.0f;   // 2*w/W - 1
        float coord1 = (float)(n >> 6) * 0.03125f - 1.0f;   // 2*h/H - 1
        float m0 = coord0 + o0 * 0.03125f - 0.015625f;      // + 2*off/W - 1/W
        float m1 = coord1 + o1 * 0.03125f - 0.015625f;

        float na = -(0.5f * LOG2E) * ca;
        float nb = -LOG2E * cb;
        float nc = -(0.5f * LOG2E) * cc;

        params4[pix * 2 + 0] = make_float4(m0, m1, na, nb);
        params4[pix * 2 + 1] = make_float4(nc, r, g, bl);
    }
}

// ---------------------------------------------------------------------------
// Kernel 2: fused render + reduce. Block = (b, ptile of 32 pixels), 1024 thr.
// All 4096 Gaussians of batch b staged in LDS (padded: float4 stride 257/seg).
// lane = seg(0..31) + 32*pixhalf; wave supplies 2 pixels; thread integrates
// 128 Gaussians; 5-step shfl_xor reduce over seg lanes; lane seg==0 writes.
// alpha = exp2(na*dx^2 + nc*dy^2 + nb*dx*dy), gated on exponent<=0.
// ---------------------------------------------------------------------------
__global__ __launch_bounds__(1024) void render_kernel(
        const float4* __restrict__ params4,
        float* __restrict__ out) {
    extern __shared__ float4 lp[];   // 32 segs * 257 float4 = 131584 B
    int t = threadIdx.x;
    int bi = blockIdx.x;
    int ptile = bi & 127;            // 32-pixel tile
    int b     = bi >> 7;

    // stage: 8192 float4s, swizzled dest (seg*257 + j*2 + half)
    const float4* src = params4 + b * (NPIX * 2);
    #pragma unroll
    for (int i = 0; i < 8; ++i) {
        int idx  = t + i * 1024;     // 0..8191
        int nn   = idx >> 1;
        int half = idx & 1;
        int seg  = nn >> 7;
        int j    = nn & 127;
        lp[seg * SEG_STRIDE4 + j * 2 + half] = src[idx];
    }
    __syncthreads();

    int lane   = t & 63;
    int wave   = t >> 6;
    int seg    = lane & 31;
    int pixloc = wave * 2 + (lane >> 5);     // 0..31
    int p = ptile * 32 + pixloc;             // 0..4095

    float px = (float)(p & 63) * 0.03125f - 1.0f;
    float py = (float)(p >> 6) * 0.03125f - 1.0f;

    const float4* seg_base = lp + seg * SEG_STRIDE4;
    float ar = 0.f, ag = 0.f, ab = 0.f;
    #pragma unroll 8
    for (int j = 0; j < RSEGLEN; ++j) {
        float4 q0 = seg_base[2 * j];
        float4 q1 = seg_base[2 * j + 1];
        float dx = px - q0.x;
        float dy = py - q0.y;
        float tt = fmaf(q0.z, dx * dx,
                   fmaf(q1.x, dy * dy, q0.w * (dx * dy)));
        float alpha = (tt <= 0.0f) ? __builtin_amdgcn_exp2f(tt) : 0.0f;
        ar = fmaf(alpha, q1.y, ar);
        ag = fmaf(alpha, q1.z, ag);
        ab = fmaf(alpha, q1.w, ab);
    }

    // reduce over the 32 seg-lanes (pixhalf bit 5 preserved by xor<32)
    #define GSUM(v) { v += __shfl_xor(v, 1); v += __shfl_xor(v, 2); \
                      v += __shfl_xor(v, 4); v += __shfl_xor(v, 8); \
                      v += __shfl_xor(v, 16); }
    GSUM(ar) GSUM(ag) GSUM(ab)
    #undef GSUM

    if (seg == 0) {
        ar = fminf(fmaxf(ar, 0.0f), 1.0f);
        ag = fminf(fmaxf(ag, 0.0f), 1.0f);
        ab = fminf(fmaxf(ab, 0.0f), 1.0f);
        out[(b * 3 + 0) * NPIX + p] = ar;
        out[(b * 3 + 1) * NPIX + p] = ag;
        out[(b * 3 + 2) * NPIX + p] = ab;
    }
}

// ---------------------------------------------------------------------------
extern "C" void kernel_launch(void* const* d_in, const int* in_sizes, int n_in,
                              void* d_out, int out_size, void* d_ws, size_t ws_size,
                              hipStream_t stream) {
    const float* inp    = (const float*)d_in[0];  // (2,3,64,64)
    const float* enc_w  = (const float*)d_in[1];  // (64,3,3,3)
    const float* enc_b  = (const float*)d_in[2];  // (64,)
    const float* head_w = (const float*)d_in[3];  // (36,64)
    const float* head_b = (const float*)d_in[4];  // (36,)
    float* out = (float*)d_out;                   // (2,3,64,64)

    float4* params4 = (float4*)d_ws;              // BN*2 float4 = 256 KB

    params_kernel<<<128, 256, 0, stream>>>(inp, enc_w, enc_b,
                                           head_w, head_b, params4);
    size_t shmem = (size_t)RSEG * SEG_STRIDE4 * sizeof(float4);  // 131584 B
    render_kernel<<<BATCH * (NPIX / 32), 1024, shmem, stream>>>(params4, out);
}